// Round 3
// baseline (682.782 us; speedup 1.0000x reference)
//
#include <hip/hip_runtime.h>

// StyleGAN2 upsample_2d (factor=2, k=[1,3,3,1], gain=1) via polyphase 2-tap
// filter per dimension. Input: (8, 256, 256, 64) NHWC fp32.
// Output: (8, 511, 511, 64) fp32 (lhs_dilation form: (H-1)*2+1 + 3 - 4 + 1 = 511).
//
// Per-dim weights: oy even -> taps (x[oy/2-1], x[oy/2]) * (0.25, 0.75)
//                  oy odd  -> taps (x[(oy-1)/2], x[(oy-1)/2+1]) * (0.75, 0.25)
// iy0 = (oy-1)>>1 (arithmetic shift handles oy=0 -> -1). Only low edge clips.

typedef float fv4 __attribute__((ext_vector_type(4)));

namespace {
constexpr int Hh = 256;
constexpr int Ww = 256;
constexpr int CV = 16;             // 64 channels / 4 floats per float4
constexpr int OH = 2 * Hh - 1;     // 511
constexpr int OW = 2 * Ww - 1;     // 511
constexpr int IN_ROW = Ww * CV;    // float4 elements per input row (4096)
constexpr int IN_IMG = Hh * IN_ROW;
}

__global__ __launch_bounds__(256) void upfir2x_kernel(const fv4* __restrict__ x,
                                                      fv4* __restrict__ out,
                                                      int nq) {
    const int stride = gridDim.x * blockDim.x;
    for (int q = blockIdx.x * blockDim.x + threadIdx.x; q < nq; q += stride) {
        const int c4  = q & (CV - 1);
        const int pix = q >> 4;
        const int ox  = pix % OW;
        const int t   = pix / OW;
        const int oy  = t % OH;
        const int b   = t / OH;

        const int ix0 = (ox - 1) >> 1;       // may be -1 at ox==0
        const int iy0 = (oy - 1) >> 1;       // may be -1 at oy==0
        const float wy0 = (oy & 1) ? 0.75f : 0.25f;
        const float wx0 = (ox & 1) ? 0.75f : 0.25f;
        const float wy1 = 1.0f - wy0;
        const float wx1 = 1.0f - wx0;

        // Branchless edge handling: clamp index, zero the weight.
        const float wya = (iy0 >= 0) ? wy0 : 0.0f;
        const float wxa = (ix0 >= 0) ? wx0 : 0.0f;
        const int iyc = (iy0 >= 0) ? iy0 : 0;
        const int ixc = (ix0 >= 0) ? ix0 : 0;
        const int iy1 = iy0 + 1;             // always in [0, 255]
        const int ix1 = ix0 + 1;             // always in [0, 255]

        const int row0 = b * IN_IMG + iyc * IN_ROW + c4;
        const int row1 = b * IN_IMG + iy1 * IN_ROW + c4;

        const fv4 v00 = x[row0 + ixc * CV];
        const fv4 v01 = x[row0 + ix1 * CV];
        const fv4 v10 = x[row1 + ixc * CV];
        const fv4 v11 = x[row1 + ix1 * CV];

        const fv4 r = wya * (wxa * v00 + wx1 * v01)
                    + wy1 * (wxa * v10 + wx1 * v11);

        __builtin_nontemporal_store(r, &out[q]);
    }
}

extern "C" void kernel_launch(void* const* d_in, const int* in_sizes, int n_in,
                              void* d_out, int out_size, void* d_ws, size_t ws_size,
                              hipStream_t stream) {
    const fv4* x = (const fv4*)d_in[0];
    fv4* out = (fv4*)d_out;
    const int nq = out_size >> 2;            // float4 count: 8*511*511*64/4

    const int block = 256;
    int grid = 8192;                          // 32 blocks/CU queued, grid-stride
    const int maxg = (nq + block - 1) / block;
    if (grid > maxg) grid = maxg;

    hipLaunchKernelGGL(upfir2x_kernel, dim3(grid), dim3(block), 0, stream,
                       x, out, nq);
}